// Round 5
// baseline (138.902 us; speedup 1.0000x reference)
//
#include <hip/hip_runtime.h>
#include <hip/hip_bf16.h>
#include <math.h>

// Problem constants (fixed by reference)
#define NFRAMES 32
#define NPED    128
#define HDIM    64
#define KDIM    4096     // G*G*H
#define OUTD    64
#define EPSV    1e-5f
#define NBLK    256      // NFRAMES * (NPED/16)
#define PSTR8   516      // 512 + 4 f32 pad (eighth-K pool rows)
#define WSTR    520      // 512 + 8 bf16 pad (Wt slice rows)

typedef __attribute__((ext_vector_type(8))) short  short8;
typedef __attribute__((ext_vector_type(4))) float  floatx4;

static __device__ __forceinline__ unsigned short f2bf(float f) {
    union { float f; unsigned u; } v; v.f = f;
    unsigned r = v.u + 0x7fffu + ((v.u >> 16) & 1u);   // RNE (no NaNs here)
    return (unsigned short)(r >> 16);
}
static __device__ __forceinline__ float bf2f(unsigned short s) {
    union { unsigned u; float f; } v; v.u = ((unsigned)s) << 16;
    return v.f;
}

// Kernel 0: Wt[o][k] = bf16(W[k][o]) via LDS-tiled transpose (round-2 verified)
__global__ void k_wt(const float* __restrict__ W, unsigned short* __restrict__ Wt) {
    __shared__ float T[64 * 65];
    const int t  = threadIdx.x;
    const int k0 = blockIdx.x * 64;
    #pragma unroll
    for (int it = 0; it < 16; ++it) {
        int idx = it * 256 + t;
        int kl = idx >> 6, o = idx & 63;
        T[kl * 65 + o] = W[(size_t)(k0 + kl) * OUTD + o];
    }
    __syncthreads();
    #pragma unroll
    for (int it = 0; it < 8; ++it) {
        int idx = it * 256 + t;
        int o = idx >> 5, kl = (idx & 31) * 2;
        unsigned v = (unsigned)f2bf(T[kl * 65 + o]) |
                     ((unsigned)f2bf(T[(kl + 1) * 65 + o]) << 16);
        *(unsigned*)(Wt + (size_t)o * KDIM + k0 + kl) = v;
    }
}

// Kernel 1: fused pool+GEMM, K processed in 8 eighths (512 k each).
// Per pass: zero P32 slice + stage Wt k-slice to LDS (coalesced), scatter cells
// of this eighth (LDS atomics, hs staged bf16 in LDS), MFMA accumulate in regs.
// One block per (frame, 16-ped chunk): 256 blocks, 256 threads (4 waves).
// LDS total 116,992 B  (< 132,608 empirically-validated max).
__global__ __launch_bounds__(256, 1) void k_fused(
    const float* __restrict__ hs, const float* __restrict__ pos,
    const unsigned short* __restrict__ Wt,
    float* __restrict__ x, float* __restrict__ psumT, float* __restrict__ psumsqT)
{
    __shared__ float P32[16 * PSTR8];                // 33,024 B (eighth-K f32 pool)
    __shared__ unsigned short WtL[64 * WSTR];        // 66,560 B (Wt k-slice)
    __shared__ unsigned short hsL[NPED * HDIM];      // 16,384 B
    __shared__ float posL[NPED * 2];                 //  1,024 B

    const int tid   = threadIdx.x;
    const int bid   = blockIdx.x;
    const int f     = bid >> 3;
    const int chunk = bid & 7;
    const int lane  = tid & 63;
    const int w     = tid >> 6;
    const int m     = lane & 15;
    const int quad  = lane >> 4;

    posL[tid] = pos[f * (NPED * 2) + tid];
    const float* hsF = hs + f * (NPED * HDIM);
    #pragma unroll
    for (int it = 0; it < 32; ++it) {                // stage hs -> LDS bf16
        int idx = it * 256 + tid;
        hsL[idx] = f2bf(hsF[idx]);
    }

    floatx4 acc = (floatx4){0.f, 0.f, 0.f, 0.f};     // 16x16 D-tile: rows=peds, cols=o

    for (int pass = 0; pass < 8; ++pass) {
        __syncthreads();                             // prev GEMM (or staging) done
        // zero pool slice + stage Wt slice [64 o][512 k] (coalesced dwordx4)
        for (int idx = tid; idx < 16 * PSTR8; idx += 256) P32[idx] = 0.f;
        #pragma unroll
        for (int it = 0; it < 16; ++it) {
            int c = it * 256 + tid;                  // 4096 chunks of 8 bf16
            int o = c >> 6, seg = c & 63;
            short8 v = *(const short8*)(Wt + (size_t)o * KDIM + pass * 512 + seg * 8);
            *(short8*)(WtL + o * WSTR + seg * 8) = v;
        }
        __syncthreads();

        // ---- scatter this eighth: lane = j (per half), wave w owns rows w*4..w*4+3 ----
        #pragma unroll
        for (int half = 0; half < 2; ++half) {
            const int j0 = half * 64 + lane;
            const float xj = posL[j0 * 2], yj = posL[j0 * 2 + 1];
            #pragma unroll
            for (int r = 0; r < 4; ++r) {
                const int row = w * 4 + r;
                const int iF  = chunk * 16 + row;
                const float xi = posL[iF * 2], yi = posL[iF * 2 + 1];
                const float tlx = xi - 1.0f, tly = yi + 1.0f;
                bool valid = (xj > tlx) & (yj < tly) & (xj < xi + 1.0f) &
                             (yj > yi - 1.0f) & (j0 != iF);
                int gx = (int)floorf((xj - tlx) * 4.0f);   // exact: (x/NS)*G == x*4
                int gy = (int)floorf((tly - yj) * 4.0f);
                int c  = gx + 8 * gy;                      // 0..63 when valid
                unsigned long long msk = __ballot(valid && ((c >> 3) == pass));
                while (msk) {                              // wave-uniform scalar loop
                    int jb[4], cc[4]; float hv[4]; bool act[4];
                    #pragma unroll
                    for (int t = 0; t < 4; ++t) {          // batch 4: overlap LDS latency
                        act[t] = (msk != 0ULL);
                        jb[t]  = act[t] ? (__ffsll(msk) - 1) : 0;
                        msk   &= (msk - 1);
                        cc[t]  = __builtin_amdgcn_readlane(c, jb[t]);
                        hv[t]  = bf2f(hsL[(half * 64 + jb[t]) * HDIM + lane]);
                    }
                    #pragma unroll
                    for (int t = 0; t < 4; ++t)
                        if (act[t])
                            atomicAdd(&P32[row * PSTR8 + (cc[t] & 7) * HDIM + lane], hv[t]);
                }
            }
        }
        __syncthreads();                             // atomics drained

        // ---- GEMM over this eighth: acc += P[16,512] @ WtL[w-tile]^T ----
        const float* Prow = P32 + m * PSTR8;         // A: m = lane&15
        const unsigned short* wRow = WtL + (w * 16 + m) * WSTR;  // B: n = lane&15
        #pragma unroll
        for (int kc = 0; kc < 16; ++kc) {
            int k0 = kc * 32 + quad * 8;             // k = quad*8 + elem
            floatx4 p0 = *(const floatx4*)(Prow + k0);
            floatx4 p1 = *(const floatx4*)(Prow + k0 + 4);
            union { floatx4 fv; unsigned uv[4]; } U0, U1;
            U0.fv = p0; U1.fv = p1;
            union { unsigned u[4]; short8 sv; } A;   // truncate f32->bf16, pack pairs
            A.u[0] = __builtin_amdgcn_perm(U0.uv[1], U0.uv[0], 0x07060302u);
            A.u[1] = __builtin_amdgcn_perm(U0.uv[3], U0.uv[2], 0x07060302u);
            A.u[2] = __builtin_amdgcn_perm(U1.uv[1], U1.uv[0], 0x07060302u);
            A.u[3] = __builtin_amdgcn_perm(U1.uv[3], U1.uv[2], 0x07060302u);
            short8 bf = *(const short8*)(wRow + k0);
            acc = __builtin_amdgcn_mfma_f32_16x16x32_bf16(A.sv, bf, acc, 0, 0, 0);
        }
    }

    // ---- epilogue: x write + BN partials (bias b cancels through BN) ----
    const int ibase = f * NPED + chunk * 16;
    float s1 = 0.f, s2 = 0.f;
    #pragma unroll
    for (int r = 0; r < 4; ++r) {
        float v = acc[r];
        int row = quad * 4 + r;                      // D: row = quad*4+reg, col = lane&15
        x[(size_t)(ibase + row) * OUTD + w * 16 + m] = v;
        s1 += v; s2 += v * v;
    }
    s1 += __shfl_xor(s1, 16); s1 += __shfl_xor(s1, 32);
    s2 += __shfl_xor(s2, 16); s2 += __shfl_xor(s2, 32);
    if (lane < 16) {                                 // transposed for coalesced k_stats
        psumT  [(w * 16 + lane) * NBLK + bid] = s1;
        psumsqT[(w * 16 + lane) * NBLK + bid] = s2;
    }
}

// Kernel 2: reduce per-block partials -> mean / invstd per output column (round-2 verified)
__global__ void k_stats(const float* __restrict__ psumT, const float* __restrict__ psumsqT,
                        float* __restrict__ mean, float* __restrict__ invstd) {
    int o = blockIdx.x;      // 64 blocks
    int t = threadIdx.x;     // 64 threads (1 wave)
    float s1 = 0.f, s2 = 0.f;
    #pragma unroll
    for (int i = 0; i < NBLK / 64; ++i) {
        s1 += psumT [o * NBLK + i * 64 + t];
        s2 += psumsqT[o * NBLK + i * 64 + t];
    }
    #pragma unroll
    for (int d = 1; d < 64; d <<= 1) {
        s1 += __shfl_xor(s1, d);
        s2 += __shfl_xor(s2, d);
    }
    if (t == 0) {
        const float inv_n = 1.0f / (float)(NFRAMES * NPED);
        float mu  = s1 * inv_n;
        float var = s2 * inv_n - mu * mu;            // biased (training-mode BN)
        mean[o]   = mu;
        invstd[o] = rsqrtf(var + EPSV);
    }
}

// Kernel 3: BN apply + ReLU, float4 vectorized (round-2 verified)
__global__ void k_apply(const float* __restrict__ x, const float* __restrict__ mean,
                        const float* __restrict__ invstd, const float* __restrict__ gamma,
                        const float* __restrict__ beta, float* __restrict__ out) {
    int g = blockIdx.x * 256 + threadIdx.x;          // 65536 float4 groups
    int oq = g & 15;
    float4 xv = ((const float4*)x)[g];
    float4 mu = ((const float4*)mean)[oq];
    float4 is = ((const float4*)invstd)[oq];
    float4 ga = ((const float4*)gamma)[oq];
    float4 be = ((const float4*)beta)[oq];
    float4 r;
    r.x = (xv.x - mu.x) * is.x * ga.x + be.x;
    r.y = (xv.y - mu.y) * is.y * ga.y + be.y;
    r.z = (xv.z - mu.z) * is.z * ga.z + be.z;
    r.w = (xv.w - mu.w) * is.w * ga.w + be.w;
    r.x = r.x > 0.f ? r.x : 0.f;
    r.y = r.y > 0.f ? r.y : 0.f;
    r.z = r.z > 0.f ? r.z : 0.f;
    r.w = r.w > 0.f ? r.w : 0.f;
    ((float4*)out)[g] = r;
}

extern "C" void kernel_launch(void* const* d_in, const int* in_sizes, int n_in,
                              void* d_out, int out_size, void* d_ws, size_t ws_size,
                              hipStream_t stream) {
    const float* hs    = (const float*)d_in[0];  // hidden_states [4096,64]
    const float* pos   = (const float*)d_in[1];  // all_pos [4096,2]
    const float* W     = (const float*)d_in[2];  // [4096,64]
    // d_in[3] = b: cancels exactly through BatchNorm -> unused
    const float* gamma = (const float*)d_in[4];
    const float* beta  = (const float*)d_in[5];
    // d_in[6] = seq_start_end: frames are uniform (i*128), hardcoded

    char* ws = (char*)d_ws;                          // total use ~2.2 MB
    unsigned short* Wt = (unsigned short*)ws;        // 512 KB @ 0
    float* x       = (float*)(ws + 0x100000);        // 1 MB
    float* psumT   = (float*)(ws + 0x200000);        // 64 KB
    float* psumsqT = (float*)(ws + 0x210000);        // 64 KB
    float* mean    = (float*)(ws + 0x220000);
    float* invstd  = mean + OUTD;

    k_wt   <<<KDIM / 64, 256, 0, stream>>>(W, Wt);
    k_fused<<<NBLK, 256, 0, stream>>>(hs, pos, Wt, x, psumT, psumsqT);
    k_stats<<<OUTD, 64, 0, stream>>>(psumT, psumsqT, mean, invstd);
    k_apply<<<(NFRAMES * NPED * OUTD / 4) / 256, 256, 0, stream>>>(x, mean, invstd, gamma, beta,
                                                                   (float*)d_out);
}

// Round 6
// 134.526 us; speedup vs baseline: 1.0325x; 1.0325x over previous
//
#include <hip/hip_runtime.h>
#include <hip/hip_bf16.h>
#include <math.h>

// Problem constants (fixed by reference)
#define NFRAMES 32
#define NPED    128
#define HDIM    64
#define KDIM    4096     // G*G*H
#define OUTD    64
#define EPSV    1e-5f
#define PSTR    516      // 8 cells * 64 h + 4 f32 pad
#define NROWS   4096     // S*N

typedef __attribute__((ext_vector_type(8))) short  short8;
typedef __attribute__((ext_vector_type(4))) float  floatx4;

static __device__ __forceinline__ unsigned short f2bf(float f) {
    union { float f; unsigned u; } v; v.f = f;
    unsigned r = v.u + 0x7fffu + ((v.u >> 16) & 1u);   // RNE (no NaNs here)
    return (unsigned short)(r >> 16);
}

// Kernel 0: transpose W -> Wt[o][k] bf16 (round-2 verified logic) + zero x/gs/flag.
// 64 blocks x 256 threads.
__global__ void k_prep(const float* __restrict__ W, unsigned short* __restrict__ Wt,
                       float* __restrict__ zbase) {
    __shared__ float T[64 * 65];
    const int t  = threadIdx.x;
    const int k0 = blockIdx.x * 64;
    // zero x (262144 f32) + gs1(64) + gs2(64) + flag(1): 262273 floats, grid-stride
    for (int idx = blockIdx.x * 256 + t; idx < NROWS * OUTD + 129; idx += 64 * 256)
        zbase[idx] = 0.f;
    #pragma unroll
    for (int it = 0; it < 16; ++it) {
        int idx = it * 256 + t;
        int kl = idx >> 6, o = idx & 63;
        T[kl * 65 + o] = W[(size_t)(k0 + kl) * OUTD + o];
    }
    __syncthreads();
    #pragma unroll
    for (int it = 0; it < 8; ++it) {
        int idx = it * 256 + t;
        int o = idx >> 5, kl = (idx & 31) * 2;
        unsigned v = (unsigned)f2bf(T[kl * 65 + o]) |
                     ((unsigned)f2bf(T[(kl + 1) * 65 + o]) << 16);
        *(unsigned*)(Wt + (size_t)o * KDIM + k0 + kl) = v;
    }
}

// Kernel 1: fused pool+GEMM, one block per (frame, 16-ped chunk, K-eighth).
// 2048 blocks x 256 threads; LDS ~34 KB, VGPR<=128 -> 4 blocks/CU (16 waves).
// Pool slice [16 peds][8 cells * 64 h] f32 via LDS atomics; GEMM K=512 with
// B-fragments gathered from L2-resident Wt; f32 atomicAdd into global x.
__global__ __launch_bounds__(256, 4) void k_fused(
    const float* __restrict__ hs, const float* __restrict__ pos,
    const unsigned short* __restrict__ Wt, float* __restrict__ x)
{
    __shared__ float P32[16 * PSTR];                 // 33,024 B
    __shared__ float posL[NPED * 2];                 //  1,024 B

    const int tid   = threadIdx.x;
    const int bid   = blockIdx.x;
    const int f     = bid >> 6;                      // frame 0..31
    const int chunk = (bid >> 3) & 7;                // 16-ped chunk 0..7
    const int kq    = bid & 7;                       // K-eighth 0..7 (cells kq*8..+8)
    const int lane  = tid & 63;
    const int w     = tid >> 6;
    const int m     = lane & 15;
    const int quad  = lane >> 4;

    posL[tid] = pos[f * (NPED * 2) + tid];
    for (int idx = tid; idx < 16 * PSTR; idx += 256) P32[idx] = 0.f;
    __syncthreads();

    const float* hsF = hs + f * (NPED * HDIM);

    // ---- scatter this eighth: lane = j (per half), wave w owns rows w*4..w*4+3 ----
    #pragma unroll
    for (int half = 0; half < 2; ++half) {
        const int j0 = half * 64 + lane;
        const float xj = posL[j0 * 2], yj = posL[j0 * 2 + 1];
        #pragma unroll
        for (int r = 0; r < 4; ++r) {
            const int row = w * 4 + r;
            const int iF  = chunk * 16 + row;
            const float xi = posL[iF * 2], yi = posL[iF * 2 + 1];
            const float tlx = xi - 1.0f, tly = yi + 1.0f;
            bool valid = (xj > tlx) & (yj < tly) & (xj < xi + 1.0f) &
                         (yj > yi - 1.0f) & (j0 != iF);
            int gx = (int)floorf((xj - tlx) * 4.0f);     // exact: (x/NS)*G == x*4
            int gy = (int)floorf((tly - yj) * 4.0f);
            int c  = gx + 8 * gy;                        // 0..63 when valid
            unsigned long long msk = __ballot(valid && ((c >> 3) == kq));
            while (msk) {                                // wave-uniform, ~1 batch avg
                int jb[4], cc[4]; float hv[4]; bool act[4];
                #pragma unroll
                for (int t = 0; t < 4; ++t) {
                    act[t] = (msk != 0ULL);
                    jb[t]  = act[t] ? (__ffsll(msk) - 1) : 0;
                    msk   &= (msk - 1);
                    cc[t]  = __builtin_amdgcn_readlane(c, jb[t]);
                    hv[t]  = hsF[(half * 64 + jb[t]) * HDIM + lane];  // coalesced 256B, L2-hot
                }
                #pragma unroll
                for (int t = 0; t < 4; ++t)
                    if (act[t])
                        atomicAdd(&P32[row * PSTR + (cc[t] & 7) * HDIM + lane], hv[t]);
            }
        }
    }
    __syncthreads();

    // ---- GEMM: acc[16 ped x 16 o per wave] += P[16,512] @ Wt[kq-slice]^T ----
    floatx4 acc = (floatx4){0.f, 0.f, 0.f, 0.f};
    const float* Prow = P32 + m * PSTR;                          // A: row = lane&15
    const unsigned short* wRow = Wt + (size_t)(w * 16 + m) * KDIM + kq * 512;  // B: o = w*16+(lane&15)
    #pragma unroll
    for (int kc = 0; kc < 16; ++kc) {
        int k0 = kc * 32 + quad * 8;                             // k = quad*8 + elem
        floatx4 p0 = *(const floatx4*)(Prow + k0);
        floatx4 p1 = *(const floatx4*)(Prow + k0 + 4);
        union { floatx4 fv; unsigned uv[4]; } U0, U1;
        U0.fv = p0; U1.fv = p1;
        union { unsigned u[4]; short8 sv; } A;                   // f32->bf16 truncate-pack
        A.u[0] = __builtin_amdgcn_perm(U0.uv[1], U0.uv[0], 0x07060302u);
        A.u[1] = __builtin_amdgcn_perm(U0.uv[3], U0.uv[2], 0x07060302u);
        A.u[2] = __builtin_amdgcn_perm(U1.uv[1], U1.uv[0], 0x07060302u);
        A.u[3] = __builtin_amdgcn_perm(U1.uv[3], U1.uv[2], 0x07060302u);
        short8 bf = *(const short8*)(wRow + k0);                 // 16B L2 gather
        acc = __builtin_amdgcn_mfma_f32_16x16x32_bf16(A.sv, bf, acc, 0, 0, 0);
    }

    // ---- epilogue: accumulate partial x (one add per (i,o) per K-eighth) ----
    const int ibase = f * NPED + chunk * 16;
    #pragma unroll
    for (int r = 0; r < 4; ++r) {
        int row = quad * 4 + r;                      // D: row = quad*4+reg, col = lane&15
        atomicAdd(&x[(size_t)(ibase + row) * OUTD + w * 16 + m], acc[r]);
    }
}

// Kernel 2: BN stats (device-wide via atomics + flag spin over 64 co-resident
// blocks) + apply + ReLU. Block b owns rows [b*64, b*64+64).
__global__ __launch_bounds__(256, 1) void k_bn(
    const float* __restrict__ x, const float* __restrict__ gamma,
    const float* __restrict__ beta, float* gs1, float* gs2, unsigned* flag,
    float* __restrict__ out)
{
    __shared__ float xs[64 * 64];
    __shared__ float ps1[256], ps2[256];
    __shared__ float muL[64], isL[64];
    const int tid = threadIdx.x;
    const int b   = blockIdx.x;

    for (int idx = tid; idx < 4096; idx += 256)
        xs[idx] = x[(size_t)b * 4096 + idx];
    __syncthreads();

    // per-block column partials
    {
        const int o = tid & 63, q = tid >> 6;
        float s1 = 0.f, s2 = 0.f;
        #pragma unroll
        for (int rr = 0; rr < 16; ++rr) {
            float v = xs[(q * 16 + rr) * 64 + o];
            s1 += v; s2 += v * v;
        }
        ps1[tid] = s1; ps2[tid] = s2;
    }
    __syncthreads();
    if (tid < 64) {
        float S1 = ps1[tid] + ps1[64 + tid] + ps1[128 + tid] + ps1[192 + tid];
        float S2 = ps2[tid] + ps2[64 + tid] + ps2[128 + tid] + ps2[192 + tid];
        atomicAdd(&gs1[tid], S1);                    // device-scope by default
        atomicAdd(&gs2[tid], S2);
    }
    __syncthreads();
    __threadfence();
    if (tid == 0) {
        __hip_atomic_fetch_add(flag, 1u, __ATOMIC_ACQ_REL, __HIP_MEMORY_SCOPE_AGENT);
        while (__hip_atomic_load(flag, __ATOMIC_ACQUIRE, __HIP_MEMORY_SCOPE_AGENT) < 64u)
            __builtin_amdgcn_s_sleep(8);
    }
    __syncthreads();
    __threadfence();

    if (tid < 64) {
        const float inv_n = 1.0f / (float)NROWS;
        float mu  = gs1[tid] * inv_n;
        float var = gs2[tid] * inv_n - mu * mu;      // biased (training-mode BN)
        muL[tid] = mu;
        isL[tid] = rsqrtf(var + EPSV);
    }
    __syncthreads();

    for (int idx = tid; idx < 4096; idx += 256) {
        int o = idx & 63;
        float v = (xs[idx] - muL[o]) * isL[o] * gamma[o] + beta[o];
        out[(size_t)b * 4096 + idx] = v > 0.f ? v : 0.f;
    }
}

extern "C" void kernel_launch(void* const* d_in, const int* in_sizes, int n_in,
                              void* d_out, int out_size, void* d_ws, size_t ws_size,
                              hipStream_t stream) {
    const float* hs    = (const float*)d_in[0];  // hidden_states [4096,64]
    const float* pos   = (const float*)d_in[1];  // all_pos [4096,2]
    const float* W     = (const float*)d_in[2];  // [4096,64]
    // d_in[3] = b: cancels exactly through BatchNorm -> unused
    const float* gamma = (const float*)d_in[4];
    const float* beta  = (const float*)d_in[5];
    // d_in[6] = seq_start_end: frames are uniform (i*128), hardcoded

    char* ws = (char*)d_ws;                          // ~1.6 MB used
    unsigned short* Wt = (unsigned short*)ws;        // 512 KB @ 0
    float* x      = (float*)(ws + 0x100000);         // 1 MB (zeroed by k_prep)
    float* gs1    = x + NROWS * OUTD;                // 64 f32 (zeroed)
    float* gs2    = gs1 + OUTD;                      // 64 f32 (zeroed)
    unsigned* flag = (unsigned*)(gs2 + OUTD);        // 1 u32 (zeroed)

    k_prep <<<64, 256, 0, stream>>>(W, Wt, x);
    k_fused<<<2048, 256, 0, stream>>>(hs, pos, Wt, x);
    k_bn   <<<64, 256, 0, stream>>>(x, gamma, beta, gs1, gs2, flag, (float*)d_out);
}